// Round 4
// baseline (365.857 us; speedup 1.0000x reference)
//
#include <hip/hip_runtime.h>

// ---------------------------------------------------------------------------
// RegionalCrossAttention on MI355X (gfx950).  fp32 in / fp32 out.
// B=2, n=8, L=4096, Lt=77, d=1024, ctx=768, H=16 heads x 64.
//
// Round-11 changes vs round-10 (317.6 us, attn_b 75.4 us, latency-bound,
// all pipes <25%, 4 waves/SIMD):
//  * attn q-tile HALVED: each block = 64 q-rows (4 waves x 16 rows, the mi
//    dimension deleted), grid 1024 -> 2048 = 8 blocks/CU = 32 waves/CU
//    (occupancy cap).  Doubles the number of independent dependency chains
//    per SIMD (4 -> 8 waves) to cover the serial QK->softmax->P->PV chain.
//    __launch_bounds__(256,8) pins VGPR <= 64 (required for 8 waves/SIMD).
//  * (b,h)-sharing block swizzle retained (round-10: FETCH_SIZE halved).
//  * vf0 register hoist dropped (register pressure, unproven win).
// ---------------------------------------------------------------------------

typedef __bf16 bf16;
typedef __bf16 bf16x8 __attribute__((ext_vector_type(8)));
typedef __bf16 bf16x4 __attribute__((ext_vector_type(4)));
typedef float  f32x4  __attribute__((ext_vector_type(4)));

#define MFMA16(a, b, c) __builtin_amdgcn_mfma_f32_16x16x32_bf16((a), (b), (c), 0, 0, 0)

// v_mfma_f32_16x16x32_bf16 layouts (HW-verified, learn_hip m89/m120):
//   A: lane holds A[m = lane&15][k = 8*(lane>>4) + j], j=0..7
//   B: lane holds B[k = 8*(lane>>4) + j][n = lane&15]
//   D: lane,reg r holds D[m = 4*(lane>>4) + r][n = lane&15]

__device__ inline bf16x8 cvt8(const float* p) {
  f32x4 a = *(const f32x4*)p;
  f32x4 b = *(const f32x4*)(p + 4);
  bf16x8 r;
  r[0] = (bf16)a[0]; r[1] = (bf16)a[1]; r[2] = (bf16)a[2]; r[3] = (bf16)a[3];
  r[4] = (bf16)b[0]; r[5] = (bf16)b[1]; r[6] = (bf16)b[2]; r[7] = (bf16)b[3];
  return r;
}

// ---------------------------------------------------------------------------
// All four weight transposes in one launch.  grid = (32, 112).
// ---------------------------------------------------------------------------
__global__ __launch_bounds__(256) void transpose_all(
    const float* __restrict__ Wq, const float* __restrict__ Wk,
    const float* __restrict__ Wv, const float* __restrict__ Wo,
    bf16* __restrict__ WqT, bf16* __restrict__ WkT,
    bf16* __restrict__ WvT, bf16* __restrict__ WoT) {
  __shared__ bf16 tile[32][33];
  int tx = threadIdx.x & 31, ty = threadIdx.x >> 5;
  int bx = blockIdx.x;
  int byg = blockIdx.y;
  const float* in;
  bf16* out;
  int R, by;
  if (byg < 32)      { in = Wq; out = WqT; R = 1024; by = byg; }
  else if (byg < 56) { in = Wk; out = WkT; R = 768;  by = byg - 32; }
  else if (byg < 80) { in = Wv; out = WvT; R = 768;  by = byg - 56; }
  else               { in = Wo; out = WoT; R = 1024; by = byg - 80; }
  const int C = 1024;
  int c = bx * 32 + tx;
#pragma unroll
  for (int i = 0; i < 32; i += 8) {
    int r = by * 32 + ty + i;
    tile[ty + i][tx] = (bf16)in[(size_t)r * C + c];
  }
  __syncthreads();
#pragma unroll
  for (int i = 0; i < 32; i += 8) {
    out[(size_t)(bx * 32 + ty + i) * R + by * 32 + tx] = tile[tx][ty + i];
  }
}

// ---------------------------------------------------------------------------
// Q GEMM (fast path): Qb_bf16[8192,1024] = (x @ WqT^T) * 0.125.  64m x 256n,
// BK=32, A staged in double-buffered LDS, 4 waves (64n each).
// ---------------------------------------------------------------------------
__global__ __launch_bounds__(256) void gemm_q_b(const float* __restrict__ A,
                                                const bf16* __restrict__ BT,
                                                bf16* __restrict__ C) {
  __shared__ __align__(16) bf16 asA[2][64 * 32];
  const int tid = threadIdx.x;
  const int lane = tid & 63, wave = tid >> 6;
  const int l16 = lane & 15, quad = lane >> 4;
  const int m0 = blockIdx.y * 64;
  const int n0 = blockIdx.x * 256 + wave * 64;
  const int srow = tid >> 2, scol = (tid & 3) * 8;
  const float* aptr = A + (size_t)(m0 + srow) * 1024 + scol;

  *(bf16x8*)(&asA[0][srow * 32 + scol]) = cvt8(aptr);

  f32x4 acc[4][4];
#pragma unroll
  for (int i = 0; i < 4; i++)
#pragma unroll
    for (int j = 0; j < 4; j++)
#pragma unroll
      for (int r = 0; r < 4; r++) acc[i][j][r] = 0.f;

  for (int kt = 0; kt < 32; kt++) {
    bf16x8 wnext;
    if (kt + 1 < 32) wnext = cvt8(aptr + (kt + 1) * 32);
    __syncthreads();
    const bf16* ab = &asA[kt & 1][0];
    bf16x8 a[4], b[4];
#pragma unroll
    for (int mi = 0; mi < 4; mi++)
      a[mi] = *(const bf16x8*)(ab + (mi * 16 + l16) * 32 + quad * 8);
#pragma unroll
    for (int ni = 0; ni < 4; ni++)
      b[ni] = *(const bf16x8*)(BT + (size_t)(n0 + ni * 16 + l16) * 1024 + kt * 32 + quad * 8);
#pragma unroll
    for (int mi = 0; mi < 4; mi++)
#pragma unroll
      for (int ni = 0; ni < 4; ni++) acc[mi][ni] = MFMA16(a[mi], b[ni], acc[mi][ni]);
    if (kt + 1 < 32)
      *(bf16x8*)(&asA[(kt + 1) & 1][srow * 32 + scol]) = wnext;
  }

#pragma unroll
  for (int mi = 0; mi < 4; mi++)
#pragma unroll
    for (int r = 0; r < 4; r++) {
      int row = m0 + mi * 16 + quad * 4 + r;
#pragma unroll
      for (int ni = 0; ni < 4; ni++)
        C[(size_t)row * 1024 + n0 + ni * 16 + l16] = (bf16)(acc[mi][ni][r] * 0.125f);
    }
}

// Q GEMM (fallback): fp32 out, also pre-scaled by 0.125
__global__ __launch_bounds__(256) void gemm_q_f(const float* __restrict__ A,
                                                const bf16* __restrict__ BT,
                                                float* __restrict__ C) {
  __shared__ __align__(16) bf16 asA[2][64 * 32];
  const int tid = threadIdx.x;
  const int lane = tid & 63, wave = tid >> 6;
  const int l16 = lane & 15, quad = lane >> 4;
  const int m0 = blockIdx.y * 64;
  const int n0 = blockIdx.x * 256 + wave * 64;
  const int srow = tid >> 2, scol = (tid & 3) * 8;
  const float* aptr = A + (size_t)(m0 + srow) * 1024 + scol;

  *(bf16x8*)(&asA[0][srow * 32 + scol]) = cvt8(aptr);

  f32x4 acc[4][4];
#pragma unroll
  for (int i = 0; i < 4; i++)
#pragma unroll
    for (int j = 0; j < 4; j++)
#pragma unroll
      for (int r = 0; r < 4; r++) acc[i][j][r] = 0.f;

  for (int kt = 0; kt < 32; kt++) {
    bf16x8 wnext;
    if (kt + 1 < 32) wnext = cvt8(aptr + (kt + 1) * 32);
    __syncthreads();
    const bf16* ab = &asA[kt & 1][0];
    bf16x8 a[4], b[4];
#pragma unroll
    for (int mi = 0; mi < 4; mi++)
      a[mi] = *(const bf16x8*)(ab + (mi * 16 + l16) * 32 + quad * 8);
#pragma unroll
    for (int ni = 0; ni < 4; ni++)
      b[ni] = *(const bf16x8*)(BT + (size_t)(n0 + ni * 16 + l16) * 1024 + kt * 32 + quad * 8);
#pragma unroll
    for (int mi = 0; mi < 4; mi++)
#pragma unroll
      for (int ni = 0; ni < 4; ni++) acc[mi][ni] = MFMA16(a[mi], b[ni], acc[mi][ni]);
    if (kt + 1 < 32) {
      *(bf16x8*)(&asA[(kt + 1) & 1][srow * 32 + scol]) = wnext;
    }
  }

#pragma unroll
  for (int mi = 0; mi < 4; mi++)
#pragma unroll
    for (int r = 0; r < 4; r++) {
      int row = m0 + mi * 16 + quad * 4 + r;
#pragma unroll
      for (int ni = 0; ni < 4; ni++)
        C[(size_t)row * 1024 + n0 + ni * 16 + l16] = acc[mi][ni][r] * 0.125f;
    }
}

// ---------------------------------------------------------------------------
// K projection body with padded store: Kp[bn][80][1024] bf16; rows 77..79 = 0.
// ---------------------------------------------------------------------------
__device__ __forceinline__ void gemm_k_body(const float* __restrict__ text,
                                            const bf16* __restrict__ WkT,
                                            bf16* __restrict__ Kp) {
  const int tid = threadIdx.x;
  const int lane = tid & 63, wave = tid >> 6;
  const int l16 = lane & 15, quad = lane >> 4;
  const int m0 = (wave >> 1) * 64;
  const int n0 = blockIdx.x * 128 + (wave & 1) * 64;
  const int bn = blockIdx.y;
  const float* A = text + (size_t)bn * 77 * 768;
  bf16* dst = Kp + (size_t)bn * 80 * 1024;

  f32x4 acc[4][4];
#pragma unroll
  for (int i = 0; i < 4; i++)
#pragma unroll
    for (int j = 0; j < 4; j++)
#pragma unroll
      for (int r = 0; r < 4; r++) acc[i][j][r] = 0.f;

  for (int k0 = 0; k0 < 768; k0 += 32) {
    bf16x8 a[4], b[4];
#pragma unroll
    for (int mi = 0; mi < 4; mi++) {
      int row = m0 + mi * 16 + l16;
      if (row >= 77) row = 76;
      a[mi] = cvt8(A + (size_t)row * 768 + k0 + quad * 8);
    }
#pragma unroll
    for (int ni = 0; ni < 4; ni++)
      b[ni] = *(const bf16x8*)(WkT + (size_t)(n0 + ni * 16 + l16) * 768 + k0 + quad * 8);
#pragma unroll
    for (int mi = 0; mi < 4; mi++)
#pragma unroll
      for (int ni = 0; ni < 4; ni++) acc[mi][ni] = MFMA16(a[mi], b[ni], acc[mi][ni]);
  }

#pragma unroll
  for (int mi = 0; mi < 4; mi++)
#pragma unroll
    for (int r = 0; r < 4; r++) {
      int t = m0 + mi * 16 + quad * 4 + r;
      if (t < 77) {
#pragma unroll
        for (int ni = 0; ni < 4; ni++)
          dst[(size_t)t * 1024 + n0 + ni * 16 + l16] = (bf16)acc[mi][ni][r];
      } else if (t < 80) {
#pragma unroll
        for (int ni = 0; ni < 4; ni++)
          dst[(size_t)t * 1024 + n0 + ni * 16 + l16] = (bf16)0.f;
      }
    }
}

// ---------------------------------------------------------------------------
// V projection body with TRANSPOSED padded store: Vt[bn][1024][96] bf16.
// ---------------------------------------------------------------------------
__device__ __forceinline__ void gemm_v_body(const float* __restrict__ text,
                                            const bf16* __restrict__ WvT,
                                            bf16* __restrict__ Vt) {
  const int tid = threadIdx.x;
  const int lane = tid & 63, wave = tid >> 6;
  const int l16 = lane & 15, quad = lane >> 4;
  const int m0 = (wave >> 1) * 64;
  const int n0 = blockIdx.x * 128 + (wave & 1) * 64;
  const int bn = blockIdx.y;
  const float* A = text + (size_t)bn * 77 * 768;
  bf16* dst = Vt + (size_t)bn * 1024 * 96;

  f32x4 acc[4][4];
#pragma unroll
  for (int i = 0; i < 4; i++)
#pragma unroll
    for (int j = 0; j < 4; j++)
#pragma unroll
      for (int r = 0; r < 4; r++) acc[i][j][r] = 0.f;

  for (int k0 = 0; k0 < 768; k0 += 32) {
    bf16x8 a[4], b[4];
#pragma unroll
    for (int mi = 0; mi < 4; mi++) {
      int row = m0 + mi * 16 + l16;
      if (row >= 77) row = 76;
      a[mi] = cvt8(A + (size_t)row * 768 + k0 + quad * 8);
    }
#pragma unroll
    for (int ni = 0; ni < 4; ni++)
      b[ni] = *(const bf16x8*)(WvT + (size_t)(n0 + ni * 16 + l16) * 768 + k0 + quad * 8);
#pragma unroll
    for (int mi = 0; mi < 4; mi++)
#pragma unroll
      for (int ni = 0; ni < 4; ni++) acc[mi][ni] = MFMA16(a[mi], b[ni], acc[mi][ni]);
  }

#pragma unroll
  for (int mi = 0; mi < 4; mi++) {
    int t0 = m0 + mi * 16 + quad * 4;
#pragma unroll
    for (int ni = 0; ni < 4; ni++) {
      int col = n0 + ni * 16 + l16;
      bf16* cbase = dst + (size_t)col * 96;
      if (t0 + 3 < 77) {
        bf16x4 w;
        w[0] = (bf16)acc[mi][ni][0]; w[1] = (bf16)acc[mi][ni][1];
        w[2] = (bf16)acc[mi][ni][2]; w[3] = (bf16)acc[mi][ni][3];
        *(bf16x4*)(cbase + t0) = w;
      } else {
#pragma unroll
        for (int r = 0; r < 4; r++) {
          int t = t0 + r;
          if (t < 77)      cbase[t] = (bf16)acc[mi][ni][r];
          else if (t < 96) cbase[t] = (bf16)0.f;
        }
      }
    }
  }
}

// Fused K+V projection: grid (8, 16, 2); z=0 -> K, z=1 -> V.
__global__ __launch_bounds__(256) void gemm_kv(const float* __restrict__ text,
                                               const bf16* __restrict__ WkT,
                                               const bf16* __restrict__ WvT,
                                               bf16* __restrict__ Kp,
                                               bf16* __restrict__ Vt) {
  if (blockIdx.z == 0) gemm_k_body(text, WkT, Kp);
  else                 gemm_v_body(text, WvT, Vt);
}

// ---------------------------------------------------------------------------
__global__ __launch_bounds__(256) void cover_kernel(const float* __restrict__ mask,
                                                    float* __restrict__ cover) {
  int tid = blockIdx.x * 256 + threadIdx.x;
  int b = tid >> 12, l = tid & 4095;
  float c = 0.f;
#pragma unroll
  for (int n = 0; n < 8; n++)
    c += (mask[(size_t)(b * 8 + n) * 4096 + l] > 0.5f) ? 1.f : 0.f;
  cover[tid] = c;
}

// ---------------------------------------------------------------------------
// Attention core.  Each block: 64 q-rows (4 waves x 16), grid 2048 =
// 8 blocks/CU = 32 waves/CU.  K/V fragments from global (L1/L2-served via
// the (b,h)-sharing swizzle).  LDS = per-wave P transpose buffer only.
// No barriers in the n-loop.
// ---------------------------------------------------------------------------
template <typename OutT, typename InT>
__device__ __forceinline__ void attn_body(const InT* Qsrc, OutT* Odst,
                                          const bf16* __restrict__ Kp,
                                          const bf16* __restrict__ Vt,
                                          const float* __restrict__ mask) {
  __shared__ __align__(16) bf16 p_lds[4][16 * 104];
  const int tid = threadIdx.x;
  const int lane = tid & 63, wave = tid >> 6;
  const int l16 = lane & 15, quad = lane >> 4;
  const int bid = blockIdx.x;
  // swizzle: qg in HIGH bits so a CU's co-resident blocks (spaced by 256
  // under round-robin dispatch) share the same (b,h) K/V working set.
  const int qg = bid >> 5;          // 0..63
  const int h  = (bid >> 1) & 15;   // 0..15
  const int b  = bid & 1;           // 0..1
  const int qrow0 = qg * 64 + wave * 16;
  bf16* pl = &p_lds[wave][0];

  // zero the t-padding columns 80..95 once (cols 96..103 never read)
  for (int i = lane; i < 16 * 16; i += 64) {
    int r = i >> 4, c = 80 + (i & 15);
    pl[r * 104 + c] = (bf16)0.f;
  }

  bf16x8 qf[2];
#pragma unroll
  for (int ks = 0; ks < 2; ks++) {
    const InT* qp = Qsrc + (size_t)(b * 4096 + qrow0 + l16) * 1024 +
                    h * 64 + ks * 32 + quad * 8;
    if constexpr (sizeof(InT) == 4) qf[ks] = cvt8((const float*)qp);
    else                            qf[ks] = *(const bf16x8*)qp;
  }

  // region mask packed to one bit per n
  unsigned rbits = 0;
#pragma unroll
  for (int n = 0; n < 8; n++)
    if (mask[(size_t)(b * 8 + n) * 4096 + qrow0 + l16] > 0.5f)
      rbits |= (1u << n);

  f32x4 oacc[4];
#pragma unroll
  for (int nt = 0; nt < 4; nt++)
#pragma unroll
    for (int r = 0; r < 4; r++) oacc[nt][r] = 0.f;

  for (int n = 0; n < 8; n++) {
    const int bn = b * 8 + n;
    const bf16* Ksrc = Kp + (size_t)bn * 80 * 1024 + h * 64;
    const bf16* Vsrc = Vt + (size_t)bn * 1024 * 96 + (size_t)h * 64 * 96;

    // ---- QK^T: K fragments straight from global (L1/L2-served) ----
    f32x4 s[5];
#pragma unroll
    for (int tt = 0; tt < 5; tt++)
#pragma unroll
      for (int r = 0; r < 4; r++) s[tt][r] = 0.f;

    __builtin_amdgcn_s_setprio(1);
#pragma unroll
    for (int tt = 0; tt < 5; tt++) {
      const bf16* kr = Ksrc + (size_t)(tt * 16 + l16) * 1024 + quad * 8;
      bf16x8 kf0 = *(const bf16x8*)kr;
      bf16x8 kf1 = *(const bf16x8*)(kr + 32);
      s[tt] = MFMA16(kf0, qf[0], s[tt]);
      s[tt] = MFMA16(kf1, qf[1], s[tt]);
    }
    __builtin_amdgcn_s_setprio(0);

    // ---- softmax -> P via LDS transpose -> registers ----
    float sum = 0.f;
#pragma unroll
    for (int tt = 0; tt < 5; tt++) {
#pragma unroll
      for (int r = 0; r < 4; r++) {
        float e = __expf(s[tt][r]);  // 0.125 scale folded into Q
        if (tt == 4 && quad * 4 + r >= 13) e = 0.f;
        s[tt][r] = e;
        sum += e;
      }
    }
    sum += __shfl_xor(sum, 16);
    sum += __shfl_xor(sum, 32);
    float rg = ((rbits >> n) & 1u) ? 1.f : 0.f;
    float scale = rg / sum;
#pragma unroll
    for (int tt = 0; tt < 5; tt++) {
      bf16x4 w;
#pragma unroll
      for (int r = 0; r < 4; r++) w[r] = (bf16)(s[tt][r] * scale);
      *(bf16x4*)(pl + l16 * 104 + tt * 16 + quad * 4) = w;
    }
    bf16x8 pfr[3];
#pragma unroll
    for (int ks = 0; ks < 3; ks++)
      pfr[ks] = *(const bf16x8*)(pl + l16 * 104 + ks * 32 + quad * 8);

    // ---- PV: V fragments straight from global ----
    __builtin_amdgcn_s_setprio(1);
#pragma unroll
    for (int ks = 0; ks < 3; ks++) {
#pragma unroll
      for (int nt = 0; nt < 4; nt++) {
        bf16x8 vf = *(const bf16x8*)(Vsrc + (size_t)(nt * 16 + l16) * 96 +
                                     ks * 32 + quad * 8);
        oacc[nt] = MFMA16(pfr[ks], vf, oacc[nt]);
      }
    }
    __builtin_amdgcn_s_setprio(0);
  }

#pragma unroll
  for (int r = 0; r < 4; r++) {
    size_t row = (size_t)(b * 4096 + qrow0 + quad * 4 + r);
#pragma unroll
    for (int nt = 0; nt < 4; nt++)
      Odst[row * 1024 + h * 64 + nt * 16 + l16] = (OutT)oacc[nt][r];
  }
}

// fast: Q bf16 (in d_out), ACC bf16 (in ws)
__global__ __launch_bounds__(256, 8) void attn_b(const bf16* Qb, bf16* ACCb,
                                                 const bf16* __restrict__ Kp,
                                                 const bf16* __restrict__ Vt,
                                                 const float* __restrict__ mask) {
  attn_body<bf16, bf16>(Qb, ACCb, Kp, Vt, mask);
}
// fallback: fp32 in-place on d_out
__global__ __launch_bounds__(256, 8) void attn_f(float* QO,
                                                 const bf16* __restrict__ Kp,
                                                 const bf16* __restrict__ Vt,
                                                 const float* __restrict__ mask) {
  attn_body<float, float>(QO, QO, Kp, Vt, mask);
}

// ---------------------------------------------------------------------------
// Fast-path final GEMM: out_f32[8192,1024] = ACCb @ WoT^T + epilogue.
// ---------------------------------------------------------------------------
__global__ __launch_bounds__(256) void gemm_wo_ep2(const bf16* __restrict__ A,
                                                   const bf16* __restrict__ BT,
                                                   const float* __restrict__ x,
                                                   const float* __restrict__ bo,
                                                   const float* __restrict__ nullf,
                                                   const float* __restrict__ cover,
                                                   float* __restrict__ out) {
  __shared__ __align__(16) bf16 asA[2][128 * 32];
  const int tid = threadIdx.x;
  const int lane = tid & 63, wave = tid >> 6;
  const int l16 = lane & 15, quad = lane >> 4;
  const int mb = blockIdx.y * 128;
  const int m0 = mb + (wave >> 1) * 64;
  const int n0 = blockIdx.x * 128 + (wave & 1) * 64;
  const int r0 = (tid * 2) >> 2, c0 = ((tid * 2) & 3) * 8;
  const int r1 = (tid * 2 + 1) >> 2, c1 = ((tid * 2 + 1) & 3) * 8;

  *(bf16x8*)(&asA[0][r0 * 32 + c0]) = *(const bf16x8*)(A + (size_t)(mb + r0) * 1024 + c0);
  *(bf16x8*)(&asA[0][r1 * 32 + c1]) = *(const bf16x8*)(A + (size_t)(mb + r1) * 1024 + c1);

  f32x4 acc[4][4];
#pragma unroll
  for (int i = 0; i < 4; i++)
#pragma unroll
    for (int j = 0; j < 4; j++)
#pragma unroll
      for (int r = 0; r < 4; r++) acc[i][j][r] = 0.f;

  for (int kt = 0; kt < 32; kt++) {
    bf16x8 p0, p1;
    if (kt + 1 < 32) {
      p0 = *(const bf16x8*)(A + (size_t)(mb + r0) * 1024 + (kt + 1) * 32 + c0);
      p1 = *(const bf16x8*)(A + (size_t)(mb + r1) * 1024 + (kt + 1) * 32 + c1);
    }
    __syncthreads();
    const bf16* ab = &asA[kt & 1][0];
    bf16x8 a[4], b[4];
#pragma unroll
    for (int mi = 0; mi < 4; mi++)
      a[mi] = *(const bf16x8*)(ab + ((wave >> 1) * 64 + mi * 16 + l16) * 32 + quad * 8);
#pragma unroll
    for (int ni = 0; ni < 4; ni++)
      b[ni] = *(const bf16x8*)(BT + (size_t)(n0 + ni * 16 + l16) * 1024 + kt * 32 + quad * 8);
#pragma unroll
    for (int mi = 0; mi < 4; mi++)
#pragma unroll
      for (int ni = 0; ni < 4; ni++) acc[mi][ni] = MFMA16(a[mi], b[ni], acc[mi][ni]);
    if (kt + 1 < 32) {
      *(bf16x8*)(&asA[(kt + 1) & 1][r0 * 32 + c0]) = p0;
      *(bf16x8*)(&asA[(kt + 1) & 1][r1 * 32 + c1]) = p1;
    }
  }

#pragma unroll
  for (int mi = 0; mi < 4; mi++)
#pragma unroll
    for (int r = 0; r < 4; r++) {
      int row = m0 + mi * 16 + quad * 4 + r;
      float cv = cover[row];
#pragma unroll
      for (int ni = 0; ni < 4; ni++) {
        int col = n0 + ni * 16 + l16;
        float v = acc[mi][ni][r] + cv * bo[col] + (1.f - cv) * nullf[col] +
                  x[(size_t)row * 1024 + col];
        out[(size_t)row * 1024 + col] = v;
      }
    }
}

// ---------------------------------------------------------------------------
// Fallback in-place final GEMM (round-7 version).
// ---------------------------------------------------------------------------
__global__ __launch_bounds__(512) void gemm_wo_ep(float* QO,
                                                  const bf16* __restrict__ WoT,
                                                  const float* __restrict__ x,
                                                  const float* __restrict__ bo,
                                                  const float* __restrict__ nullf,
                                                  const float* __restrict__ cover) {
  __shared__ __align__(16) bf16 lds_a[32 * 32 * 32];
  const int tid = threadIdx.x;
  const int lane = tid & 63, wv = tid >> 6;
  const int l16 = lane & 15, quad = lane >> 4;
  const int m0 = blockIdx.x * 32;

#pragma unroll
  for (int c = 0; c < 16; c++) {
    int ch = c * 512 + tid;
    int row = ch >> 8;
    int pos4 = (ch & 255) * 4;
    int kt = pos4 >> 5, kin = pos4 & 31;
    f32x4 v = *(const f32x4*)(QO + (size_t)(m0 + row) * 1024 + pos4);
    bf16x4 w;
    w[0] = (bf16)v[0]; w[1] = (bf16)v[1]; w[2] = (bf16)v[2]; w[3] = (bf16)v[3];
    *(bf16x4*)(lds_a + kt * 1024 + row * 32 + kin) = w;
  }
  __syncthreads();

  const int n0 = wv * 128;
  f32x4 acc[2][8];
#pragma unroll
  for (int mi = 0; mi < 2; mi++)
#pragma unroll
    for (int ni = 0; ni < 8; ni++)
#pragma unroll
      for (int r = 0; r < 4; r++) acc[mi][ni][r] = 0.f;

  for (int kt = 0; kt < 32; kt++) {
    bf16x8 a[2];
#pragma unroll
    for (int mi = 0; mi < 2; mi++)
      a[mi] = *(const bf16x8*)(lds_a + kt * 1024 + (mi * 16 + l16) * 32 + quad * 8);
    bf16x8 bfr[8];
#pragma unroll
    for (int ni = 0; ni < 8; ni++)
      bfr[ni] = *(const bf16x8*)(WoT + (size_t)(n0 + ni * 16 + l16) * 1024 + kt * 32 + quad * 8);
#pragma unroll
    for (int mi = 0; mi < 2; mi++)
#pragma unroll
      for (int ni = 0; ni < 8; ni++) acc[mi][ni] = MFMA16(a[mi], bfr[ni], acc[mi][ni]);
  }

#pragma unroll
  for (int mi = 0; mi < 2; mi++)
#pragma unroll
    for (int r = 0; r < 4; r++) {
      int row = m0 + mi * 16 + quad * 4 + r;
      float cv = cover[row];
#pragma unroll
      for (int ni = 0; ni < 8; ni++) {
        int col = n0 + ni * 16 + l16;
        float v = acc[mi][ni][r] + cv * bo[col] + (1.f - cv) * nullf[col] +
                  x[(size_t)row * 1024 + col];
        QO[(size_t)row * 1024 + col] = v;
      }
    }
}

// ---------------------------------------------------------------------------
extern "C" void kernel_launch(void* const* d_in, const int* in_sizes, int n_in,
                              void* d_out, int out_size, void* d_ws, size_t ws_size,
                              hipStream_t stream) {
  const float* x     = (const float*)d_in[0];
  const float* masks = (const float*)d_in[1];
  const float* text  = (const float*)d_in[2];
  const float* Wq    = (const float*)d_in[3];
  const float* Wk    = (const float*)d_in[4];
  const float* Wv    = (const float*)d_in[5];
  const float* Wo    = (const float*)d_in[6];
  const float* bo    = (const float*)d_in[7];
  const float* nullf = (const float*)d_in[8];
  float* out = (float*)d_out;

  bf16* ws  = (bf16*)d_ws;
  bf16* WqT = ws;                  // 1024*1024
  bf16* WkT = WqT + 1048576;       // 1024*768
  bf16* WvT = WkT + 786432;        // 1024*768
  bf16* WoT = WvT + 786432;        // 1024*1024
  bf16* Kp  = WoT + 1048576;       // 16*80*1024
  bf16* Vt  = Kp + 1310720;        // 16*1024*96
  float* cover = (float*)(Vt + 1572864);          // 8192 f32
  bf16* ACCb = (bf16*)(cover + 8192);             // 8192*1024 bf16 (fast path)
  const size_t NEEDED = 13139968 + 16777216;      // 29,917,184 B

  transpose_all<<<dim3(32, 112), 256, 0, stream>>>(Wq, Wk, Wv, Wo, WqT, WkT, WvT, WoT);
  gemm_kv<<<dim3(8, 16, 2), 256, 0, stream>>>(text, WkT, WvT, Kp, Vt);
  cover_kernel<<<32, 256, 0, stream>>>(masks, cover);

  if (ws_size >= NEEDED) {
    bf16* Qb = (bf16*)d_out;  // bf16 Q in d_out; dead after attn_b
    gemm_q_b<<<dim3(4, 128), 256, 0, stream>>>(x, WqT, Qb);
    attn_b<<<2048, 256, 0, stream>>>(Qb, ACCb, Kp, Vt, masks);
    gemm_wo_ep2<<<dim3(8, 64), 256, 0, stream>>>(ACCb, WoT, x, bo, nullf, cover, out);
  } else {
    gemm_q_f<<<dim3(4, 128), 256, 0, stream>>>(x, WqT, out);
    attn_f<<<2048, 256, 0, stream>>>(out, Kp, Vt, masks);
    gemm_wo_ep<<<256, 512, 0, stream>>>(out, WoT, x, bo, nullf, cover);
  }
}

// Round 5
// 288.207 us; speedup vs baseline: 1.2694x; 1.2694x over previous
//
#include <hip/hip_runtime.h>

// ---------------------------------------------------------------------------
// RegionalCrossAttention on MI355X (gfx950).  fp32 in / fp32 out.
// B=2, n=8, L=4096, Lt=77, d=1024, ctx=768, H=16 heads x 64.
//
// Round-12 changes vs round-11 (365.9 us; attn 129 us VGPR-starved at 32):
//  * attn REVERTED to the round-8 structure (best measured: 64.8 us):
//    K/V staged in LDS, 4 waves x 32 q-rows, p_lds[4][16*104], 4 blocks/CU,
//    launch_bounds(256,4).  Rounds 9-11 (no staging / swizzle / half-tile)
//    all regressed; the per-wave latency-chain theory is dead.
//  * LAUNCH FUSION (the actual lever: ~12 us/launch measured r7->r8):
//      - cover folded into transpose_all       (grid (32,113), y==112)
//      - gemm_q_b + gemm_kv -> one proj_qkv    (768 flat blocks)
//    Fast path: 6 -> 4 launches.
// ---------------------------------------------------------------------------

typedef __bf16 bf16;
typedef __bf16 bf16x8 __attribute__((ext_vector_type(8)));
typedef __bf16 bf16x4 __attribute__((ext_vector_type(4)));
typedef float  f32x4  __attribute__((ext_vector_type(4)));

#define MFMA16(a, b, c) __builtin_amdgcn_mfma_f32_16x16x32_bf16((a), (b), (c), 0, 0, 0)

// v_mfma_f32_16x16x32_bf16 layouts (HW-verified, learn_hip m89/m120):
//   A: lane holds A[m = lane&15][k = 8*(lane>>4) + j], j=0..7
//   B: lane holds B[k = 8*(lane>>4) + j][n = lane&15]
//   D: lane,reg r holds D[m = 4*(lane>>4) + r][n = lane&15]

__device__ inline bf16x8 cvt8(const float* p) {
  f32x4 a = *(const f32x4*)p;
  f32x4 b = *(const f32x4*)(p + 4);
  bf16x8 r;
  r[0] = (bf16)a[0]; r[1] = (bf16)a[1]; r[2] = (bf16)a[2]; r[3] = (bf16)a[3];
  r[4] = (bf16)b[0]; r[5] = (bf16)b[1]; r[6] = (bf16)b[2]; r[7] = (bf16)b[3];
  return r;
}

// ---------------------------------------------------------------------------
// Four weight transposes + cover, one launch.  grid = (32, 113).
//   y in [0,32)   : Wq (1024x1024)
//   y in [32,56)  : Wk (768x1024)
//   y in [56,80)  : Wv (768x1024)
//   y in [80,112) : Wo (1024x1024)
//   y == 112      : cover (32 x-blocks x 256 threads = 8192 rows)
// ---------------------------------------------------------------------------
__global__ __launch_bounds__(256) void transpose_all(
    const float* __restrict__ Wq, const float* __restrict__ Wk,
    const float* __restrict__ Wv, const float* __restrict__ Wo,
    bf16* __restrict__ WqT, bf16* __restrict__ WkT,
    bf16* __restrict__ WvT, bf16* __restrict__ WoT,
    const float* __restrict__ mask, float* __restrict__ cover) {
  __shared__ bf16 tile[32][33];
  int bx = blockIdx.x;
  int byg = blockIdx.y;
  if (byg == 112) {
    int tid = bx * 256 + threadIdx.x;
    int b = tid >> 12, l = tid & 4095;
    float c = 0.f;
#pragma unroll
    for (int n = 0; n < 8; n++)
      c += (mask[(size_t)(b * 8 + n) * 4096 + l] > 0.5f) ? 1.f : 0.f;
    cover[tid] = c;
    return;
  }
  int tx = threadIdx.x & 31, ty = threadIdx.x >> 5;
  const float* in;
  bf16* out;
  int R, by;
  if (byg < 32)      { in = Wq; out = WqT; R = 1024; by = byg; }
  else if (byg < 56) { in = Wk; out = WkT; R = 768;  by = byg - 32; }
  else if (byg < 80) { in = Wv; out = WvT; R = 768;  by = byg - 56; }
  else               { in = Wo; out = WoT; R = 1024; by = byg - 80; }
  const int C = 1024;
  int c = bx * 32 + tx;
#pragma unroll
  for (int i = 0; i < 32; i += 8) {
    int r = by * 32 + ty + i;
    tile[ty + i][tx] = (bf16)in[(size_t)r * C + c];
  }
  __syncthreads();
#pragma unroll
  for (int i = 0; i < 32; i += 8) {
    out[(size_t)(bx * 32 + ty + i) * R + by * 32 + tx] = tile[tx][ty + i];
  }
}

// ---------------------------------------------------------------------------
// Q GEMM body: Qb_bf16[8192,1024] = (x @ WqT^T) * 0.125.  64m x 256n, BK=32,
// A staged in double-buffered LDS, 4 waves (64n each).  Scale is the softmax
// 1/sqrt(64), exact in bf16 (power of two).
// ---------------------------------------------------------------------------
__device__ __forceinline__ void gemm_q_body(const float* __restrict__ A,
                                            const bf16* __restrict__ BT,
                                            bf16* __restrict__ C,
                                            int bx, int by) {
  __shared__ __align__(16) bf16 asA[2][64 * 32];
  const int tid = threadIdx.x;
  const int lane = tid & 63, wave = tid >> 6;
  const int l16 = lane & 15, quad = lane >> 4;
  const int m0 = by * 64;
  const int n0 = bx * 256 + wave * 64;
  const int srow = tid >> 2, scol = (tid & 3) * 8;
  const float* aptr = A + (size_t)(m0 + srow) * 1024 + scol;

  *(bf16x8*)(&asA[0][srow * 32 + scol]) = cvt8(aptr);

  f32x4 acc[4][4];
#pragma unroll
  for (int i = 0; i < 4; i++)
#pragma unroll
    for (int j = 0; j < 4; j++)
#pragma unroll
      for (int r = 0; r < 4; r++) acc[i][j][r] = 0.f;

  for (int kt = 0; kt < 32; kt++) {
    bf16x8 wnext;
    if (kt + 1 < 32) wnext = cvt8(aptr + (kt + 1) * 32);
    __syncthreads();
    const bf16* ab = &asA[kt & 1][0];
    bf16x8 a[4], b[4];
#pragma unroll
    for (int mi = 0; mi < 4; mi++)
      a[mi] = *(const bf16x8*)(ab + (mi * 16 + l16) * 32 + quad * 8);
#pragma unroll
    for (int ni = 0; ni < 4; ni++)
      b[ni] = *(const bf16x8*)(BT + (size_t)(n0 + ni * 16 + l16) * 1024 + kt * 32 + quad * 8);
#pragma unroll
    for (int mi = 0; mi < 4; mi++)
#pragma unroll
      for (int ni = 0; ni < 4; ni++) acc[mi][ni] = MFMA16(a[mi], b[ni], acc[mi][ni]);
    if (kt + 1 < 32)
      *(bf16x8*)(&asA[(kt + 1) & 1][srow * 32 + scol]) = wnext;
  }

#pragma unroll
  for (int mi = 0; mi < 4; mi++)
#pragma unroll
    for (int r = 0; r < 4; r++) {
      int row = m0 + mi * 16 + quad * 4 + r;
#pragma unroll
      for (int ni = 0; ni < 4; ni++)
        C[(size_t)row * 1024 + n0 + ni * 16 + l16] = (bf16)(acc[mi][ni][r] * 0.125f);
    }
}

// ---------------------------------------------------------------------------
// K projection body with padded store: Kp[bn][80][1024] bf16; rows 77..79 = 0.
// ---------------------------------------------------------------------------
__device__ __forceinline__ void gemm_k_body(const float* __restrict__ text,
                                            const bf16* __restrict__ WkT,
                                            bf16* __restrict__ Kp,
                                            int bx, int bn) {
  const int tid = threadIdx.x;
  const int lane = tid & 63, wave = tid >> 6;
  const int l16 = lane & 15, quad = lane >> 4;
  const int m0 = (wave >> 1) * 64;
  const int n0 = bx * 128 + (wave & 1) * 64;
  const float* A = text + (size_t)bn * 77 * 768;
  bf16* dst = Kp + (size_t)bn * 80 * 1024;

  f32x4 acc[4][4];
#pragma unroll
  for (int i = 0; i < 4; i++)
#pragma unroll
    for (int j = 0; j < 4; j++)
#pragma unroll
      for (int r = 0; r < 4; r++) acc[i][j][r] = 0.f;

  for (int k0 = 0; k0 < 768; k0 += 32) {
    bf16x8 a[4], b[4];
#pragma unroll
    for (int mi = 0; mi < 4; mi++) {
      int row = m0 + mi * 16 + l16;
      if (row >= 77) row = 76;
      a[mi] = cvt8(A + (size_t)row * 768 + k0 + quad * 8);
    }
#pragma unroll
    for (int ni = 0; ni < 4; ni++)
      b[ni] = *(const bf16x8*)(WkT + (size_t)(n0 + ni * 16 + l16) * 768 + k0 + quad * 8);
#pragma unroll
    for (int mi = 0; mi < 4; mi++)
#pragma unroll
      for (int ni = 0; ni < 4; ni++) acc[mi][ni] = MFMA16(a[mi], b[ni], acc[mi][ni]);
  }

#pragma unroll
  for (int mi = 0; mi < 4; mi++)
#pragma unroll
    for (int r = 0; r < 4; r++) {
      int t = m0 + mi * 16 + quad * 4 + r;
      if (t < 77) {
#pragma unroll
        for (int ni = 0; ni < 4; ni++)
          dst[(size_t)t * 1024 + n0 + ni * 16 + l16] = (bf16)acc[mi][ni][r];
      } else if (t < 80) {
#pragma unroll
        for (int ni = 0; ni < 4; ni++)
          dst[(size_t)t * 1024 + n0 + ni * 16 + l16] = (bf16)0.f;
      }
    }
}

// ---------------------------------------------------------------------------
// V projection body with TRANSPOSED padded store: Vt[bn][1024][96] bf16.
// ---------------------------------------------------------------------------
__device__ __forceinline__ void gemm_v_body(const float* __restrict__ text,
                                            const bf16* __restrict__ WvT,
                                            bf16* __restrict__ Vt,
                                            int bx, int bn) {
  const int tid = threadIdx.x;
  const int lane = tid & 63, wave = tid >> 6;
  const int l16 = lane & 15, quad = lane >> 4;
  const int m0 = (wave >> 1) * 64;
  const int n0 = bx * 128 + (wave & 1) * 64;
  const float* A = text + (size_t)bn * 77 * 768;
  bf16* dst = Vt + (size_t)bn * 1024 * 96;

  f32x4 acc[4][4];
#pragma unroll
  for (int i = 0; i < 4; i++)
#pragma unroll
    for (int j = 0; j < 4; j++)
#pragma unroll
      for (int r = 0; r < 4; r++) acc[i][j][r] = 0.f;

  for (int k0 = 0; k0 < 768; k0 += 32) {
    bf16x8 a[4], b[4];
#pragma unroll
    for (int mi = 0; mi < 4; mi++) {
      int row = m0 + mi * 16 + l16;
      if (row >= 77) row = 76;
      a[mi] = cvt8(A + (size_t)row * 768 + k0 + quad * 8);
    }
#pragma unroll
    for (int ni = 0; ni < 4; ni++)
      b[ni] = *(const bf16x8*)(WvT + (size_t)(n0 + ni * 16 + l16) * 768 + k0 + quad * 8);
#pragma unroll
    for (int mi = 0; mi < 4; mi++)
#pragma unroll
      for (int ni = 0; ni < 4; ni++) acc[mi][ni] = MFMA16(a[mi], b[ni], acc[mi][ni]);
  }

#pragma unroll
  for (int mi = 0; mi < 4; mi++) {
    int t0 = m0 + mi * 16 + quad * 4;
#pragma unroll
    for (int ni = 0; ni < 4; ni++) {
      int col = n0 + ni * 16 + l16;
      bf16* cbase = dst + (size_t)col * 96;
      if (t0 + 3 < 77) {
        bf16x4 w;
        w[0] = (bf16)acc[mi][ni][0]; w[1] = (bf16)acc[mi][ni][1];
        w[2] = (bf16)acc[mi][ni][2]; w[3] = (bf16)acc[mi][ni][3];
        *(bf16x4*)(cbase + t0) = w;
      } else {
#pragma unroll
        for (int r = 0; r < 4; r++) {
          int t = t0 + r;
          if (t < 77)      cbase[t] = (bf16)acc[mi][ni][r];
          else if (t < 96) cbase[t] = (bf16)0.f;
        }
      }
    }
  }
}

// ---------------------------------------------------------------------------
// Fused Q + K + V projections, one launch.  Flat grid of 768 blocks:
//   bid <  512 : Q GEMM  (bx = bid&3, by = bid>>2)
//   bid >= 512 : K/V     (r = bid-512: bx = r&7, bn = (r>>3)&15, z = r>>7)
// ---------------------------------------------------------------------------
__global__ __launch_bounds__(256) void proj_qkv(const float* __restrict__ x,
                                                const bf16* __restrict__ WqT,
                                                bf16* __restrict__ Qb,
                                                const float* __restrict__ text,
                                                const bf16* __restrict__ WkT,
                                                const bf16* __restrict__ WvT,
                                                bf16* __restrict__ Kp,
                                                bf16* __restrict__ Vt) {
  const int bid = blockIdx.x;
  if (bid < 512) {
    gemm_q_body(x, WqT, Qb, bid & 3, bid >> 2);
  } else {
    const int r = bid - 512;
    const int bx = r & 7, bn = (r >> 3) & 15, kz = r >> 7;
    if (kz == 0) gemm_k_body(text, WkT, Kp, bx, bn);
    else         gemm_v_body(text, WvT, Vt, bx, bn);
  }
}

// Q GEMM (fallback): fp32 out, pre-scaled by 0.125
__global__ __launch_bounds__(256) void gemm_q_f(const float* __restrict__ A,
                                                const bf16* __restrict__ BT,
                                                float* __restrict__ C) {
  __shared__ __align__(16) bf16 asA[2][64 * 32];
  const int tid = threadIdx.x;
  const int lane = tid & 63, wave = tid >> 6;
  const int l16 = lane & 15, quad = lane >> 4;
  const int m0 = blockIdx.y * 64;
  const int n0 = blockIdx.x * 256 + wave * 64;
  const int srow = tid >> 2, scol = (tid & 3) * 8;
  const float* aptr = A + (size_t)(m0 + srow) * 1024 + scol;

  *(bf16x8*)(&asA[0][srow * 32 + scol]) = cvt8(aptr);

  f32x4 acc[4][4];
#pragma unroll
  for (int i = 0; i < 4; i++)
#pragma unroll
    for (int j = 0; j < 4; j++)
#pragma unroll
      for (int r = 0; r < 4; r++) acc[i][j][r] = 0.f;

  for (int kt = 0; kt < 32; kt++) {
    bf16x8 wnext;
    if (kt + 1 < 32) wnext = cvt8(aptr + (kt + 1) * 32);
    __syncthreads();
    const bf16* ab = &asA[kt & 1][0];
    bf16x8 a[4], b[4];
#pragma unroll
    for (int mi = 0; mi < 4; mi++)
      a[mi] = *(const bf16x8*)(ab + (mi * 16 + l16) * 32 + quad * 8);
#pragma unroll
    for (int ni = 0; ni < 4; ni++)
      b[ni] = *(const bf16x8*)(BT + (size_t)(n0 + ni * 16 + l16) * 1024 + kt * 32 + quad * 8);
#pragma unroll
    for (int mi = 0; mi < 4; mi++)
#pragma unroll
      for (int ni = 0; ni < 4; ni++) acc[mi][ni] = MFMA16(a[mi], b[ni], acc[mi][ni]);
    if (kt + 1 < 32) {
      *(bf16x8*)(&asA[(kt + 1) & 1][srow * 32 + scol]) = wnext;
    }
  }

#pragma unroll
  for (int mi = 0; mi < 4; mi++)
#pragma unroll
    for (int r = 0; r < 4; r++) {
      int row = m0 + mi * 16 + quad * 4 + r;
#pragma unroll
      for (int ni = 0; ni < 4; ni++)
        C[(size_t)row * 1024 + n0 + ni * 16 + l16] = acc[mi][ni][r] * 0.125f;
    }
}

// ---------------------------------------------------------------------------
// Attention core (round-8 structure, best measured: 64.8 us).
// LDS: kl 11520 + vl 13312 + p_lds 13312 = 38144 B -> 4 blocks/CU.
// QK^T joint for both mi (shared kl fragment reads); softmax, P-store, PV
// run per-mi so the per-wave P buffer is only 16 rows.
// ---------------------------------------------------------------------------
template <typename OutT, typename InT>
__device__ __forceinline__ void attn_body(const InT* Qsrc, OutT* Odst,
                                          const bf16* __restrict__ Kp,
                                          const bf16* __restrict__ Vt,
                                          const float* __restrict__ mask) {
  __shared__ __align__(16) bf16 kl[80 * 72];
  __shared__ __align__(16) bf16 vl[64 * 104];
  __shared__ __align__(16) bf16 p_lds[4][16 * 104];
  const int tid = threadIdx.x;
  const int lane = tid & 63, wave = tid >> 6;
  const int l16 = lane & 15, quad = lane >> 4;
  const int bid = blockIdx.x;
  const int qg = bid & 31;
  const int h = (bid >> 5) & 15;
  const int b = bid >> 9;
  const int qrow0 = qg * 128 + wave * 32;
  bf16* pl = &p_lds[wave][0];

  // zero the t-padding columns 80..95 once (cols 96..103 never read)
  for (int i = lane; i < 16 * 16; i += 64) {
    int r = i >> 4, c = 80 + (i & 15);
    pl[r * 104 + c] = (bf16)0.f;
  }

  bf16x8 qf[2][2];
#pragma unroll
  for (int mi = 0; mi < 2; mi++)
#pragma unroll
    for (int ks = 0; ks < 2; ks++) {
      const InT* qp = Qsrc + (size_t)(b * 4096 + qrow0 + mi * 16 + l16) * 1024 +
                      h * 64 + ks * 32 + quad * 8;
      if constexpr (sizeof(InT) == 4) qf[mi][ks] = cvt8((const float*)qp);
      else                            qf[mi][ks] = *(const bf16x8*)qp;
    }

  // region mask packed to one bit per n
  unsigned rbits[2];
#pragma unroll
  for (int mi = 0; mi < 2; mi++) {
    unsigned m = 0;
#pragma unroll
    for (int n = 0; n < 8; n++)
      if (mask[(size_t)(b * 8 + n) * 4096 + qrow0 + mi * 16 + l16] > 0.5f)
        m |= (1u << n);
    rbits[mi] = m;
  }

  f32x4 oacc[2][4];
#pragma unroll
  for (int mi = 0; mi < 2; mi++)
#pragma unroll
    for (int nt = 0; nt < 4; nt++)
#pragma unroll
      for (int r = 0; r < 4; r++) oacc[mi][nt][r] = 0.f;

  for (int n = 0; n < 8; n++) {
    const int bn = b * 8 + n;
    const bf16* Ksrc = Kp + (size_t)bn * 80 * 1024 + h * 64;
    const bf16* Vsrc = Vt + (size_t)bn * 1024 * 96 + (size_t)h * 64 * 96;

    for (int i = tid; i < 640; i += 256) {
      int row = i >> 3, c8 = (i & 7) * 8;
      *(bf16x8*)(kl + row * 72 + c8) = *(const bf16x8*)(Ksrc + (size_t)row * 1024 + c8);
    }
    for (int i = tid; i < 768; i += 256) {
      int row = i / 12, c8 = (i % 12) * 8;
      *(bf16x8*)(vl + row * 104 + c8) = *(const bf16x8*)(Vsrc + (size_t)row * 96 + c8);
    }
    __syncthreads();

    // joint QK^T for both mi (shares the K fragment reads)
    f32x4 s[2][5];
#pragma unroll
    for (int mi = 0; mi < 2; mi++)
#pragma unroll
      for (int tt = 0; tt < 5; tt++)
#pragma unroll
        for (int r = 0; r < 4; r++) s[mi][tt][r] = 0.f;

#pragma unroll
    for (int tt = 0; tt < 5; tt++) {
      int t = tt * 16 + l16;
      bf16x8 kf0 = *(const bf16x8*)(kl + t * 72 + quad * 8);
      bf16x8 kf1 = *(const bf16x8*)(kl + t * 72 + 32 + quad * 8);
#pragma unroll
      for (int mi = 0; mi < 2; mi++) {
        s[mi][tt] = MFMA16(kf0, qf[mi][0], s[mi][tt]);
        s[mi][tt] = MFMA16(kf1, qf[mi][1], s[mi][tt]);
      }
    }

    // per-mi: softmax -> P -> PV  (P buffer holds one mi at a time)
#pragma unroll
    for (int mi = 0; mi < 2; mi++) {
      float sum = 0.f;
#pragma unroll
      for (int tt = 0; tt < 5; tt++) {
#pragma unroll
        for (int r = 0; r < 4; r++) {
          float e = __expf(s[mi][tt][r]);  // 0.125 scale folded into Q GEMM
          if (tt == 4 && quad * 4 + r >= 13) e = 0.f;
          s[mi][tt][r] = e;
          sum += e;
        }
      }
      sum += __shfl_xor(sum, 16);
      sum += __shfl_xor(sum, 32);
      float rg = ((rbits[mi] >> n) & 1u) ? 1.f : 0.f;
      float scale = rg / sum;
#pragma unroll
      for (int tt = 0; tt < 5; tt++) {
        bf16x4 w;
#pragma unroll
        for (int r = 0; r < 4; r++) w[r] = (bf16)(s[mi][tt][r] * scale);
        *(bf16x4*)(pl + l16 * 104 + tt * 16 + quad * 4) = w;
      }

#pragma unroll
      for (int ks = 0; ks < 3; ks++) {
        bf16x8 pf = *(const bf16x8*)(pl + l16 * 104 + ks * 32 + quad * 8);
#pragma unroll
        for (int nt = 0; nt < 4; nt++) {
          bf16x8 vf = *(const bf16x8*)(vl + (nt * 16 + l16) * 104 + ks * 32 + quad * 8);
          oacc[mi][nt] = MFMA16(pf, vf, oacc[mi][nt]);
        }
      }
    }
    __syncthreads();
  }

#pragma unroll
  for (int mi = 0; mi < 2; mi++)
#pragma unroll
    for (int r = 0; r < 4; r++) {
      size_t row = (size_t)(b * 4096 + qrow0 + mi * 16 + quad * 4 + r);
#pragma unroll
      for (int nt = 0; nt < 4; nt++)
        Odst[row * 1024 + h * 64 + nt * 16 + l16] = (OutT)oacc[mi][nt][r];
    }
}

// fast: Q bf16 (in d_out), ACC bf16 (in ws)
__global__ __launch_bounds__(256, 4) void attn_b(const bf16* Qb, bf16* ACCb,
                                                 const bf16* __restrict__ Kp,
                                                 const bf16* __restrict__ Vt,
                                                 const float* __restrict__ mask) {
  attn_body<bf16, bf16>(Qb, ACCb, Kp, Vt, mask);
}
// fallback: fp32 in-place on d_out
__global__ __launch_bounds__(256, 4) void attn_f(float* QO,
                                                 const bf16* __restrict__ Kp,
                                                 const bf16* __restrict__ Vt,
                                                 const float* __restrict__ mask) {
  attn_body<float, float>(QO, QO, Kp, Vt, mask);
}

// ---------------------------------------------------------------------------
// Fast-path final GEMM: out_f32[8192,1024] = ACCb @ WoT^T + epilogue.
// 128x128 block tile, 4 waves (64x64), BK=32 double-buffered LDS A-staging.
// ---------------------------------------------------------------------------
__global__ __launch_bounds__(256) void gemm_wo_ep2(const bf16* __restrict__ A,
                                                   const bf16* __restrict__ BT,
                                                   const float* __restrict__ x,
                                                   const float* __restrict__ bo,
                                                   const float* __restrict__ nullf,
                                                   const float* __restrict__ cover,
                                                   float* __restrict__ out) {
  __shared__ __align__(16) bf16 asA[2][128 * 32];
  const int tid = threadIdx.x;
  const int lane = tid & 63, wave = tid >> 6;
  const int l16 = lane & 15, quad = lane >> 4;
  const int mb = blockIdx.y * 128;
  const int m0 = mb + (wave >> 1) * 64;
  const int n0 = blockIdx.x * 128 + (wave & 1) * 64;
  const int r0 = (tid * 2) >> 2, c0 = ((tid * 2) & 3) * 8;
  const int r1 = (tid * 2 + 1) >> 2, c1 = ((tid * 2 + 1) & 3) * 8;

  *(bf16x8*)(&asA[0][r0 * 32 + c0]) = *(const bf16x8*)(A + (size_t)(mb + r0) * 1024 + c0);
  *(bf16x8*)(&asA[0][r1 * 32 + c1]) = *(const bf16x8*)(A + (size_t)(mb + r1) * 1024 + c1);

  f32x4 acc[4][4];
#pragma unroll
  for (int i = 0; i < 4; i++)
#pragma unroll
    for (int j = 0; j < 4; j++)
#pragma unroll
      for (int r = 0; r < 4; r++) acc[i][j][r] = 0.f;

  for (int kt = 0; kt < 32; kt++) {
    bf16x8 p0, p1;
    if (kt + 1 < 32) {
      p0 = *(const bf16x8*)(A + (size_t)(mb + r0) * 1024 + (kt + 1) * 32 + c0);
      p1 = *(const bf16x8*)(A + (size_t)(mb + r1) * 1024 + (kt + 1) * 32 + c1);
    }
    __syncthreads();
    const bf16* ab = &asA[kt & 1][0];
    bf16x8 a[4], b[4];
#pragma unroll
    for (int mi = 0; mi < 4; mi++)
      a[mi] = *(const bf16x8*)(ab + ((wave >> 1) * 64 + mi * 16 + l16) * 32 + quad * 8);
#pragma unroll
    for (int ni = 0; ni < 4; ni++)
      b[ni] = *(const bf16x8*)(BT + (size_t)(n0 + ni * 16 + l16) * 1024 + kt * 32 + quad * 8);
#pragma unroll
    for (int mi = 0; mi < 4; mi++)
#pragma unroll
      for (int ni = 0; ni < 4; ni++) acc[mi][ni] = MFMA16(a[mi], b[ni], acc[mi][ni]);
    if (kt + 1 < 32) {
      *(bf16x8*)(&asA[(kt + 1) & 1][r0 * 32 + c0]) = p0;
      *(bf16x8*)(&asA[(kt + 1) & 1][r1 * 32 + c1]) = p1;
    }
  }

#pragma unroll
  for (int mi = 0; mi < 4; mi++)
#pragma unroll
    for (int r = 0; r < 4; r++) {
      int row = m0 + mi * 16 + quad * 4 + r;
      float cv = cover[row];
#pragma unroll
      for (int ni = 0; ni < 4; ni++) {
        int col = n0 + ni * 16 + l16;
        float v = acc[mi][ni][r] + cv * bo[col] + (1.f - cv) * nullf[col] +
                  x[(size_t)row * 1024 + col];
        out[(size_t)row * 1024 + col] = v;
      }
    }
}

// ---------------------------------------------------------------------------
// Fallback in-place final GEMM (round-7 version).
// ---------------------------------------------------------------------------
__global__ __launch_bounds__(512) void gemm_wo_ep(float* QO,
                                                  const bf16* __restrict__ WoT,
                                                  const float* __restrict__ x,
                                                  const float* __restrict__ bo,
                                                  const float* __restrict__ nullf,
                                                  const float* __restrict__ cover) {
  __shared__ __align__(16) bf16 lds_a[32 * 32 * 32];
  const int tid = threadIdx.x;
  const int lane = tid & 63, wv = tid >> 6;
  const int l16 = lane & 15, quad = lane >> 4;
  const int m0 = blockIdx.x * 32;

#pragma unroll
  for (int c = 0; c < 16; c++) {
    int ch = c * 512 + tid;
    int row = ch >> 8;
    int pos4 = (ch & 255) * 4;
    int kt = pos4 >> 5, kin = pos4 & 31;
    f32x4 v = *(const f32x4*)(QO + (size_t)(m0 + row) * 1024 + pos4);
    bf16x4 w;
    w[0] = (bf16)v[0]; w[1] = (bf16)v[1]; w[2] = (bf16)v[2]; w[3] = (bf16)v[3];
    *(bf16x4*)(lds_a + kt * 1024 + row * 32 + kin) = w;
  }
  __syncthreads();

  const int n0 = wv * 128;
  f32x4 acc[2][8];
#pragma unroll
  for (int mi = 0; mi < 2; mi++)
#pragma unroll
    for (int ni = 0; ni < 8; ni++)
#pragma unroll
      for (int r = 0; r < 4; r++) acc[mi][ni][r] = 0.f;

  for (int kt = 0; kt < 32; kt++) {
    bf16x8 a[2];
#pragma unroll
    for (int mi = 0; mi < 2; mi++)
      a[mi] = *(const bf16x8*)(lds_a + kt * 1024 + (mi * 16 + l16) * 32 + quad * 8);
    bf16x8 bfr[8];
#pragma unroll
    for (int ni = 0; ni < 8; ni++)
      bfr[ni] = *(const bf16x8*)(WoT + (size_t)(n0 + ni * 16 + l16) * 1024 + kt * 32 + quad * 8);
#pragma unroll
    for (int mi = 0; mi < 2; mi++)
#pragma unroll
      for (int ni = 0; ni < 8; ni++) acc[mi][ni] = MFMA16(a[mi], bfr[ni], acc[mi][ni]);
  }

#pragma unroll
  for (int mi = 0; mi < 2; mi++)
#pragma unroll
    for (int r = 0; r < 4; r++) {
      int row = m0 + mi * 16 + quad * 4 + r;
      float cv = cover[row];
#pragma unroll
      for (int ni = 0; ni < 8; ni++) {
        int col = n0 + ni * 16 + l16;
        float v = acc[mi][ni][r] + cv * bo[col] + (1.f - cv) * nullf[col] +
                  x[(size_t)row * 1024 + col];
        QO[(size_t)row * 1024 + col] = v;
      }
    }
}

// ---------------------------------------------------------------------------
extern "C" void kernel_launch(void* const* d_in, const int* in_sizes, int n_in,
                              void* d_out, int out_size, void* d_ws, size_t ws_size,
                              hipStream_t stream) {
  const float* x     = (const float*)d_in[0];
  const float* masks = (const float*)d_in[1];
  const float* text  = (const float*)d_in[2];
  const float* Wq    = (const float*)d_in[3];
  const float* Wk    = (const float*)d_in[4];
  const float* Wv    = (const float*)d_in[5];
  const float* Wo    = (const float*)d_in[6];
  const float* bo    = (const float*)d_in[7];
  const float* nullf = (const float*)d_in[8];
  float* out = (float*)d_out;

  bf16* ws  = (bf16*)d_ws;
  bf16* WqT = ws;                  // 1024*1024
  bf16* WkT = WqT + 1048576;       // 1024*768
  bf16* WvT = WkT + 786432;        // 1024*768
  bf16* WoT = WvT + 786432;        // 1024*1024
  bf16* Kp  = WoT + 1048576;       // 16*80*1024
  bf16* Vt  = Kp + 1310720;        // 16*1024*96
  float* cover = (float*)(Vt + 1572864);          // 8192 f32
  bf16* ACCb = (bf16*)(cover + 8192);             // 8192*1024 bf16 (fast path)
  const size_t NEEDED = 13139968 + 16777216;      // 29,917,184 B

  transpose_all<<<dim3(32, 113), 256, 0, stream>>>(Wq, Wk, Wv, Wo, WqT, WkT, WvT, WoT,
                                                   masks, cover);

  if (ws_size >= NEEDED) {
    bf16* Qb = (bf16*)d_out;  // bf16 Q in d_out; dead after attn_b
    proj_qkv<<<768, 256, 0, stream>>>(x, WqT, Qb, text, WkT, WvT, Kp, Vt);
    attn_b<<<1024, 256, 0, stream>>>(Qb, ACCb, Kp, Vt, masks);
    gemm_wo_ep2<<<dim3(8, 64), 256, 0, stream>>>(ACCb, WoT, x, bo, nullf, cover, out);
  } else {
    proj_qkv<<<768, 256, 0, stream>>>(x, WqT, (bf16*)d_ws /*unused dummy*/, text, WkT, WvT, Kp, Vt);
    gemm_q_f<<<dim3(4, 128), 256, 0, stream>>>(x, WqT, out);
    attn_f<<<1024, 256, 0, stream>>>(out, Kp, Vt, masks);
    gemm_wo_ep<<<256, 512, 0, stream>>>(out, WoT, x, bo, nullf, cover);
  }
}